// Round 2
// 63.072 us; speedup vs baseline: 1.0021x; 1.0021x over previous
//
#include <hip/hip_runtime.h>

#define NPART 128
#define NBATCH 256
#define NOUT 64
#define NIN 64
#define BROWS 32   // batch rows per block (unchanged -> no extra w redundancy)
#define LDK 72     // padded LDS row stride in bf16 elems (144 B -> max 2-way bank aliasing = free)
#define NTHREADS 512

typedef __attribute__((ext_vector_type(8))) short short8;          // MFMA A/B frag (8 bf16)
typedef __attribute__((ext_vector_type(4))) float floatx4;         // MFMA C/D frag
typedef __attribute__((ext_vector_type(8))) unsigned short ushortx8;
typedef __attribute__((ext_vector_type(4))) unsigned short ushortx4;

__device__ __forceinline__ unsigned short f_to_bf16(float f) {
    union { unsigned int i; float f; } v; v.f = f;
    unsigned int b = v.i;
    unsigned int r = b + 0x7FFFu + ((b >> 16) & 1u);   // RNE; finite positives only here
    return (unsigned short)(r >> 16);
}

// out[b,p,o] = logsumexp_i( x[b,p,i] + log_softmax(w[p,o,:])[i] )
//            = log( sum_i exp(x[b,p,i]) * exp(w[p,o,i]) ) - log( sum_i exp(w[p,o,i]) )
//
// R3 structure: identical algorithm/LDS layout to R2, but 512-thread blocks
// (8 waves) so the same 1024-block grid gives 32 waves/CU (full occupancy)
// instead of 16 — latency-hiding theory. Per-thread staging work halved;
// per-wave MFMA tile halved (16x16 out, 2 MFMAs). No added redundancy.
__global__ __launch_bounds__(NTHREADS, 8) void sumlayer_kernel(
    const float* __restrict__ x,   // [NBATCH][NPART][NIN] fp32
    const float* __restrict__ w,   // [NPART][NOUT][NIN] fp32
    float* __restrict__ out)       // [NBATCH][NPART][NOUT] fp32
{
    __shared__ alignas(16) unsigned short Wlds[64 * LDK];     // bf16(exp(w[p]))
    __shared__ alignas(16) unsigned short Alds[BROWS * LDK];  // bf16(exp(x)) tile
    __shared__ float wlse[64];

    const int p  = blockIdx.x;            // partition
    const int b0 = blockIdx.y * BROWS;    // batch tile origin
    const int t  = threadIdx.x;

    // ---- issue x load early (overlap with w load+process latency) ----
    const int arow = t >> 4;              // 0..31 batch row in tile
    const int asub = t & 15;              // 4 elems each
    const float* xptr = x + ((((size_t)(b0 + arow)) * NPART + p) * NIN + asub * 4);
    const float4 xv = *(const float4*)xptr;

    // ---- stage bf16(exp(weight[p])) -> Wlds, wlse[o] = log(sum_i exp(w[o,:])) ----
    {
        const int row = t >> 3;           // 0..63 out-node
        const int sub = t & 7;            // 8 elems each
        const float* wptr = w + (((size_t)p * NOUT + row) * NIN + sub * 8);
        const float4 w0 = *(const float4*)(wptr);
        const float4 w1 = *(const float4*)(wptr + 4);
        const float vals[8] = {w0.x, w0.y, w0.z, w0.w, w1.x, w1.y, w1.z, w1.w};
        float s = 0.f;
        ushortx8 e;
        #pragma unroll
        for (int j = 0; j < 8; ++j) { float ev = __expf(vals[j]); s += ev; e[j] = f_to_bf16(ev); }
        *(ushortx8*)(Wlds + row * LDK + sub * 8) = e;
        // 8 sub-lanes of a row are adjacent lanes in one wave (8 | 64)
        s += __shfl_xor(s, 1);
        s += __shfl_xor(s, 2);
        s += __shfl_xor(s, 4);
        if (sub == 0) wlse[row] = __logf(s);
    }

    // ---- stage bf16(exp(x[b0+arow, p, :])) -> Alds (4 elems/thread, coalesced) ----
    {
        const float vals[4] = {xv.x, xv.y, xv.z, xv.w};
        ushortx4 a;
        #pragma unroll
        for (int j = 0; j < 4; ++j) a[j] = f_to_bf16(__expf(vals[j]));
        *(ushortx4*)(Alds + arow * LDK + asub * 4) = a;
    }

    __syncthreads();

    // ---- MFMA: wave -> 16 batch rows x 16 out-nodes (8 waves cover 32x64) ----
    const int wv = t >> 6;            // wave 0..7
    const int l  = t & 63;
    const int ln = l & 15;
    const int q  = l >> 4;            // quad: k = q*8 + j
    const int r0 = (wv & 1) * 16;     // batch-row half within tile
    const int oh = (wv >> 1) * 16;    // out-node quarter

    // A frag: lane holds A[m = r0+ln][k = q*8+j]
    const short8 a0 = *(const short8*)(Alds + (r0 + ln) * LDK + q * 8);
    const short8 a1 = *(const short8*)(Alds + (r0 + ln) * LDK + 32 + q * 8);

    const int o = oh + ln;
    // B frag: lane holds B[k = q*8+j][n] = expw[o][k]
    const short8 bb0 = *(const short8*)(Wlds + o * LDK + q * 8);
    const short8 bb1 = *(const short8*)(Wlds + o * LDK + 32 + q * 8);

    floatx4 c = {0.f, 0.f, 0.f, 0.f};
    c = __builtin_amdgcn_mfma_f32_16x16x32_bf16(a0, bb0, c, 0, 0, 0);
    c = __builtin_amdgcn_mfma_f32_16x16x32_bf16(a1, bb1, c, 0, 0, 0);

    // ---- epilogue: D layout col(n)=ln -> o, row(m)=q*4+r -> batch row ----
    const float wl = wlse[o];
    #pragma unroll
    for (int r = 0; r < 4; ++r) {
        const int b = b0 + r0 + q * 4 + r;
        out[((size_t)b * NPART + p) * NOUT + o] = __logf(c[r]) - wl;
    }
}

extern "C" void kernel_launch(void* const* d_in, const int* in_sizes, int n_in,
                              void* d_out, int out_size, void* d_ws, size_t ws_size,
                              hipStream_t stream) {
    const float* x = (const float*)d_in[0];   // fp32 [256,128,64]
    const float* w = (const float*)d_in[1];   // fp32 [128,64,64]
    float* out = (float*)d_out;               // fp32 [256,128,64]
    dim3 grid(NPART, NBATCH / BROWS);
    sumlayer_kernel<<<grid, dim3(NTHREADS), 0, stream>>>(x, w, out);
}